// Round 5
// baseline (329.189 us; speedup 1.0000x reference)
//
#include <hip/hip_runtime.h>

// 2-layer LSTM (H=2, I=1) + dense sigmoid head.
// 4 lanes per chain (sub = layer*2 + comp), DPP quad_perm exchange,
// prescaled gate weights, product-form tail.
// NEW: half-populated waves (32 active lanes) -> 2048 waves = 2 waves/SIMD,
// so one wave's dependency stalls are filled by the other wave's issue.

typedef float f2 __attribute__((ext_vector_type(2)));

__device__ __forceinline__ float fast_sigmoid(float x) {
    float e = __builtin_amdgcn_exp2f(-1.4426950408889634f * x);
    return __builtin_amdgcn_rcpf(1.0f + e);
}

template<int CTRL>
__device__ __forceinline__ float dpp_f(float v) {
    return __int_as_float(__builtin_amdgcn_update_dpp(
        0, __float_as_int(v), CTRL, 0xF, 0xF, true));
}
// 0xB1 = [1,0,3,2] partner comp, same layer
// 0x44 = [0,1,0,1] lanes 2,3 <- lanes 0,1 (h0 own-order)
// 0x11 = [1,0,1,0] lanes 2,3 <- lanes 1,0 (h0 cross-order)

__global__ __launch_bounds__(256, 2)
void lstm2_quad_kernel(const float* __restrict__ x,
                       const float* __restrict__ Wih0, const float* __restrict__ Whh0,
                       const float* __restrict__ bih0, const float* __restrict__ bhh0,
                       const float* __restrict__ Wih1, const float* __restrict__ Whh1,
                       const float* __restrict__ bih1, const float* __restrict__ bhh1,
                       const float* __restrict__ Wd,   const float* __restrict__ bd,
                       float* __restrict__ out, int B, int T)
{
    const int lane = threadIdx.x & 63;
    if (lane >= 32) return;                 // half-populated waves: 2/SIMD

    const int wave   = threadIdx.x >> 6;    // 4 waves/block
    const int chain  = blockIdx.x * 32 + wave * 8 + (lane >> 2);
    if (chain >= B) return;
    const int  sub   = lane & 3;            // 0:L0c0 1:L0c1 2:L1c0 3:L1c1
    const int  comp  = sub & 1;
    const bool is_l1 = (sub & 2) != 0;

    const float K1 = 1.4426950408889634f;
    const float K2 = 2.8853900817779268f;   // 2*log2(e)

    // Per-lane gate coefficients, PRESCALED: i,f,o by -K1; u by +K2.
    float wa[4], wb[4], who[4], whp[4], bsv[4];
#pragma unroll
    for (int g = 0; g < 4; ++g) {
        const int j = 2 * g + comp;
        const float s = (g == 2) ? K2 : -K1;
        if (!is_l1) {
            wa[g]  = s * Wih0[j];
            wb[g]  = 0.0f;
            who[g] = s * Whh0[2 * j + comp];
            whp[g] = s * Whh0[2 * j + 1 - comp];
            bsv[g] = s * (bih0[j] + bhh0[j]);
        } else {
            wa[g]  = s * Wih1[2 * j + comp];
            wb[g]  = s * Wih1[2 * j + 1 - comp];
            who[g] = s * Whh1[2 * j + comp];
            whp[g] = s * Whh1[2 * j + 1 - comp];
            bsv[g] = s * (bih1[j] + bhh1[j]);
        }
    }
    const f2 wA_lo = {wa[0], wa[1]},  wA_hi = {wa[2], wa[3]};
    const f2 wB_lo = {wb[0], wb[1]},  wB_hi = {wb[2], wb[3]};
    const f2 wO_lo = {who[0], who[1]}, wO_hi = {who[2], who[3]};
    const f2 wP_lo = {whp[0], whp[1]}, wP_hi = {whp[2], whp[3]};
    const f2 bs_lo = {bsv[0], bsv[1]}, bs_hi = {bsv[2], bsv[3]};

    float h = 0.f, C = 0.f;            // C = K2 * c
    float hp = 0.f, ina = 0.f, inb = 0.f;

    auto step = [&](float xt) {
        const float a0 = is_l1 ? ina : xt;
        const f2 a02 = {a0, a0}, ib2 = {inb, inb}, h2 = {h, h}, hp2 = {hp, hp};
        f2 gLo = __builtin_elementwise_fma(wB_lo, ib2,
                 __builtin_elementwise_fma(wA_lo, a02, bs_lo));
        gLo    = __builtin_elementwise_fma(wO_lo, h2,
                 __builtin_elementwise_fma(wP_lo, hp2, gLo));
        f2 gHi = __builtin_elementwise_fma(wB_hi, ib2,
                 __builtin_elementwise_fma(wA_hi, a02, bs_hi));
        gHi    = __builtin_elementwise_fma(wO_hi, h2,
                 __builtin_elementwise_fma(wP_hi, hp2, gHi));
        const float e0 = __builtin_amdgcn_exp2f(gLo.x);
        const float e1 = __builtin_amdgcn_exp2f(gLo.y);
        const float e2 = __builtin_amdgcn_exp2f(gHi.x);
        const float e3 = __builtin_amdgcn_exp2f(gHi.y);
        const float A0 = 1.f + e0, A1 = 1.f + e1, A2 = 1.f + e2, A3 = 1.f + e3;
        const float Q01 = A0 * A1, Q23 = A2 * A3, A13 = A1 * A3;
        const float r   = __builtin_amdgcn_rcpf(Q01 * Q23);
        const float t2  = fmaf(K2, A2, -2.f * K2);   // K2*(A2-2)
        const float M   = t2 * A13;
        const float N   = A0 * Q23;
        const float S   = fmaf(N, C, M);
        const float OVp = Q01 * A2;
        C = r * S;
        const float ov  = OVp * r;
        const float ov2 = -2.f * ov;                 // off-chain
        const float ec = __builtin_amdgcn_exp2f(C);
        const float R  = __builtin_amdgcn_rcpf(1.f + ec);
        h = fmaf(ov2, R, ov);                        // ov*(1-2R), R->h one op
        hp  = dpp_f<0xB1>(h);
        ina = dpp_f<0x44>(h);
        inb = dpp_f<0x11>(h);
    };

    const float4* xb = reinterpret_cast<const float4*>(x + (size_t)chain * (size_t)T);
    const int nT4 = T >> 2;

    float4 cur = xb[0];
    float4 nxt = xb[1];

    // Peeled t=0: layer1 result is bogus -> reset, re-propagate h.
    step(cur.x);
    if (is_l1) { h = 0.f; C = 0.f; }
    hp  = dpp_f<0xB1>(h);
    ina = dpp_f<0x44>(h);
    inb = dpp_f<0x11>(h);
    step(cur.y); step(cur.z); step(cur.w);

    for (int t4 = 1; t4 < nT4 - 1; ++t4) {
        cur = nxt;
        nxt = xb[t4 + 1];
        step(cur.x); step(cur.y); step(cur.z); step(cur.w);
    }
    cur = nxt;
    step(cur.x); step(cur.y); step(cur.z); step(cur.w);

    // Final skewed iteration: layer1 consumes h0(T-1).
    step(0.f);

    // Lane sub==2: h = h1_0, hp = h1_1.
    if (sub == 2) {
        out[chain] = fast_sigmoid(fmaf(Wd[1], hp, fmaf(Wd[0], h, bd[0])));
    }
}

extern "C" void kernel_launch(void* const* d_in, const int* in_sizes, int n_in,
                              void* d_out, int out_size, void* d_ws, size_t ws_size,
                              hipStream_t stream)
{
    const float* x    = (const float*)d_in[0];
    const float* Wih0 = (const float*)d_in[1];
    const float* Whh0 = (const float*)d_in[2];
    const float* bih0 = (const float*)d_in[3];
    const float* bhh0 = (const float*)d_in[4];
    const float* Wih1 = (const float*)d_in[5];
    const float* Whh1 = (const float*)d_in[6];
    const float* bih1 = (const float*)d_in[7];
    const float* bhh1 = (const float*)d_in[8];
    const float* Wd   = (const float*)d_in[9];
    const float* bd   = (const float*)d_in[10];
    float* out = (float*)d_out;

    const int B = out_size;            // 16384
    const int T = in_sizes[0] / B;     // 2048

    // 32 active lanes/wave, 8 chains/wave, 4 waves/block -> 32 chains/block.
    const int blocks = (B + 31) / 32;  // 512 blocks = 2048 waves = 2/SIMD
    dim3 block(256), grid(blocks);
    lstm2_quad_kernel<<<grid, block, 0, stream>>>(x, Wih0, Whh0, bih0, bhh0,
                                                  Wih1, Whh1, bih1, bhh1, Wd, bd,
                                                  out, B, T);
}

// Round 6
// 292.718 us; speedup vs baseline: 1.1246x; 1.1246x over previous
//
#include <hip/hip_runtime.h>

// 2-layer LSTM (H=2, I=1) + dense sigmoid head.
// 4 lanes per chain (sub = layer*2 + comp), DPP quad_perm exchange.
// ALL-RATIONAL step: sigmoid/tanh via Lambert CF Pade (depth 6),
//   sigma(g) = (D+N)/(2D) of tanh(g/2);  u,tanh(c) clamped +-4.5.
// Cell update kept as a fraction c=S/(2P); tanh(c) evaluated homogeneously
// in (S,P) with exponent-bit normalization -> only 2 v_rcp_f32 per step,
// zero v_exp_f32 in the main loop.

typedef float f2 __attribute__((ext_vector_type(2)));

__device__ __forceinline__ float fast_sigmoid(float x) {
    float e = __builtin_amdgcn_exp2f(-1.4426950408889634f * x);
    return __builtin_amdgcn_rcpf(1.0f + e);
}

template<int CTRL>
__device__ __forceinline__ float dpp_f(float v) {
    return __int_as_float(__builtin_amdgcn_update_dpp(
        0, __float_as_int(v), CTRL, 0xF, 0xF, true));
}
// 0xB1 = [1,0,3,2] partner comp, same layer
// 0x44 = [0,1,0,1] lanes 2,3 <- lanes 0,1 (h0 own-order)
// 0x11 = [1,0,1,0] lanes 2,3 <- lanes 1,0 (h0 cross-order)

__global__ __launch_bounds__(256, 1)
void lstm2_rat_kernel(const float* __restrict__ x,
                      const float* __restrict__ Wih0, const float* __restrict__ Whh0,
                      const float* __restrict__ bih0, const float* __restrict__ bhh0,
                      const float* __restrict__ Wih1, const float* __restrict__ Whh1,
                      const float* __restrict__ bih1, const float* __restrict__ bhh1,
                      const float* __restrict__ Wd,   const float* __restrict__ bd,
                      float* __restrict__ out, int B, int T)
{
    const int tid   = blockIdx.x * 256 + threadIdx.x;
    const int chain = tid >> 2;
    if (chain >= B) return;
    const int  sub   = tid & 3;        // 0:L0c0 1:L0c1 2:L1c0 3:L1c1
    const int  comp  = sub & 1;
    const bool is_l1 = (sub & 2) != 0;

    // Per-lane gate coefficients. Gate g: 0=i,1=f,2=u,3=o; weight row j=2g+comp.
    // i,f,o prescaled by 0.5 (sigma(g) = (D+N)/(2D) of tanh(g/2)); u unscaled.
    float wa[4], wb[4], who[4], whp[4], bsv[4];
#pragma unroll
    for (int g = 0; g < 4; ++g) {
        const int j = 2 * g + comp;
        const float s = (g == 2) ? 1.0f : 0.5f;
        if (!is_l1) {
            wa[g]  = s * Wih0[j];
            wb[g]  = 0.0f;
            who[g] = s * Whh0[2 * j + comp];
            whp[g] = s * Whh0[2 * j + 1 - comp];
            bsv[g] = s * (bih0[j] + bhh0[j]);
        } else {
            wa[g]  = s * Wih1[2 * j + comp];
            wb[g]  = s * Wih1[2 * j + 1 - comp];
            who[g] = s * Whh1[2 * j + comp];
            whp[g] = s * Whh1[2 * j + 1 - comp];
            bsv[g] = s * (bih1[j] + bhh1[j]);
        }
    }
    const f2 wA_lo = {wa[0], wa[1]},  wA_hi = {wa[2], wa[3]};
    const f2 wB_lo = {wb[0], wb[1]},  wB_hi = {wb[2], wb[3]};
    const f2 wO_lo = {who[0], who[1]}, wO_hi = {who[2], who[3]};
    const f2 wP_lo = {whp[0], whp[1]}, wP_hi = {whp[2], whp[3]};
    const f2 bs_lo = {bsv[0], bsv[1]}, bs_hi = {bsv[2], bsv[3]};

    // Pade depth-6 CF constants (splat, hoisted to regs).
    const f2 CLIM = {4.5f, 4.5f}, CLIMN = {-4.5f, -4.5f};
    const f2 C21 = {21.f, 21.f}, C1260 = {1260.f, 1260.f};
    const f2 C10395 = {10395.f, 10395.f};
    const f2 C210 = {210.f, 210.f}, C4725 = {4725.f, 4725.f};

    float h = 0.f, c = 0.f;            // own (layer,comp) state; c normalized
    float hp = 0.f, ina = 0.f, inb = 0.f;

    auto step = [&](float xt) {
        const float a0 = is_l1 ? ina : xt;
        const f2 a02 = {a0, a0}, ib2 = {inb, inb}, h2 = {h, h}, hp2 = {hp, hp};
        // gate dots; h enters at the last fma.
        f2 gLo = __builtin_elementwise_fma(wB_lo, ib2,
                 __builtin_elementwise_fma(wA_lo, a02, bs_lo));
        gLo    = __builtin_elementwise_fma(wO_lo, h2,
                 __builtin_elementwise_fma(wP_lo, hp2, gLo));
        f2 gHi = __builtin_elementwise_fma(wB_hi, ib2,
                 __builtin_elementwise_fma(wA_hi, a02, bs_hi));
        gHi    = __builtin_elementwise_fma(wO_hi, h2,
                 __builtin_elementwise_fma(wP_hi, hp2, gHi));
        // clamp (only u-gate can exceed; harmless for others)
        gLo = __builtin_elementwise_min(__builtin_elementwise_max(gLo, CLIMN), CLIM);
        gHi = __builtin_elementwise_min(__builtin_elementwise_max(gHi, CLIMN), CLIM);
        // tanh Pade: N = g(10395+1260t+21t^2), D = 10395+4725t+210t^2+t^3, t=g^2
        const f2 tLo = gLo * gLo, tHi = gHi * gHi;
        f2 nLo = __builtin_elementwise_fma(
                   __builtin_elementwise_fma(C21, tLo, C1260), tLo, C10395);
        f2 nHi = __builtin_elementwise_fma(
                   __builtin_elementwise_fma(C21, tHi, C1260), tHi, C10395);
        const f2 NLo = gLo * nLo, NHi = gHi * nHi;
        f2 dLo = __builtin_elementwise_fma(
                   __builtin_elementwise_fma(tLo + C210, tLo, C4725), tLo, C10395);
        f2 dHi = __builtin_elementwise_fma(
                   __builtin_elementwise_fma(tHi + C210, tHi, C4725), tHi, C10395);
        const float Ni = NLo.x, Nf = NLo.y, Nu = NHi.x, No = NHi.y;
        const float Di = dLo.x, Df = dLo.y, Du = dHi.x, Do = dHi.y;
        // c_new = S/(2*P2):
        const float DiDu = Di * Du;
        const float Af = Df + Nf;          // 2*Df*sigma(f)
        const float Bi = Di + Ni;          // 2*Di*sigma(i)
        const float Co = Do + No;          // 2*Do*sigma(o)
        const float T1 = Af * DiDu;
        const float T2b = (Bi * Nu) * Df;
        const float S  = fmaf(T1, c, T2b);
        const float P2 = Df * DiDu;        // > 10395^3, always normal, finite
        // normalize: em = mant(P2) in [0.5,1); Sn = S * 2^(-E-2) so c = Sn/em
        const unsigned ub = __float_as_uint(P2);
        const float em = __uint_as_float((ub & 0x007FFFFFu) | 0x3F000000u);
        const float sc = __uint_as_float(0x7E000000u - (ub & 0x7F800000u));
        const float Sn = S * sc;
        // c renormalize (off critical path: needed only next step)
        c = Sn * __builtin_amdgcn_rcpf(em);
        // clamp tanh input to +-4.5 (ratio Sc/em)
        const float lim = 4.5f * em;
        const float Sc = fminf(fmaxf(Sn, -lim), lim);
        // homogeneous tanh: tanh(Sc/em) = em*Sc*NUM/DEN
        //   NUM = 10395v2+1260uv+21u^2 (0.5 of sigma(o) folded: halved consts)
        //   DEN = 10395v3+4725uv2+210u^2v+u^3 ; v=em^2,u=Sc^2
        const float v = em * em, u = Sc * Sc;
        const float v2 = v * v, v3 = v2 * v;
        const float qd = 10395.f * v3;
        const float d1 = fmaf(fmaf(210.f, v, u), u, 4725.f * v2);
        const float DEN = fmaf(d1, u, qd);
        const float n1 = fmaf(10.5f, u, 630.f * v);
        const float NUM = fmaf(n1, u, 5197.5f * v2);
        const float AD = Do * DEN;
        const float r2 = __builtin_amdgcn_rcpf(AD);
        const float SNC = ((Sc * NUM) * em) * Co;
        h = SNC * r2;                      // sigma(o)*tanh(c_new)
        hp  = dpp_f<0xB1>(h);
        ina = dpp_f<0x44>(h);
        inb = dpp_f<0x11>(h);
    };

    const float4* xb = reinterpret_cast<const float4*>(x + (size_t)chain * (size_t)T);
    const int nT4 = T >> 2;

    float4 cur = xb[0];
    float4 nxt = xb[1];

    // Peeled t=0: layer1 result is bogus -> reset, re-propagate h.
    step(cur.x);
    if (is_l1) { h = 0.f; c = 0.f; }
    hp  = dpp_f<0xB1>(h);
    ina = dpp_f<0x44>(h);
    inb = dpp_f<0x11>(h);
    step(cur.y); step(cur.z); step(cur.w);

    for (int t4 = 1; t4 < nT4 - 1; ++t4) {
        cur = nxt;
        nxt = xb[t4 + 1];
        step(cur.x); step(cur.y); step(cur.z); step(cur.w);
    }
    cur = nxt;
    step(cur.x); step(cur.y); step(cur.z); step(cur.w);

    // Final skewed iteration: layer1 consumes h0(T-1).
    step(0.f);

    // Lane sub==2: h = h1_0, hp = h1_1.
    if (sub == 2) {
        out[chain] = fast_sigmoid(fmaf(Wd[1], hp, fmaf(Wd[0], h, bd[0])));
    }
}

extern "C" void kernel_launch(void* const* d_in, const int* in_sizes, int n_in,
                              void* d_out, int out_size, void* d_ws, size_t ws_size,
                              hipStream_t stream)
{
    const float* x    = (const float*)d_in[0];
    const float* Wih0 = (const float*)d_in[1];
    const float* Whh0 = (const float*)d_in[2];
    const float* bih0 = (const float*)d_in[3];
    const float* bhh0 = (const float*)d_in[4];
    const float* Wih1 = (const float*)d_in[5];
    const float* Whh1 = (const float*)d_in[6];
    const float* bih1 = (const float*)d_in[7];
    const float* bhh1 = (const float*)d_in[8];
    const float* Wd   = (const float*)d_in[9];
    const float* bd   = (const float*)d_in[10];
    float* out = (float*)d_out;

    const int B = out_size;            // 16384
    const int T = in_sizes[0] / B;     // 2048

    const int threads = B * 4;
    dim3 block(256), grid((threads + 255) / 256);
    lstm2_rat_kernel<<<grid, block, 0, stream>>>(x, Wih0, Whh0, bih0, bhh0,
                                                 Wih1, Whh1, bih1, bhh1, Wd, bd,
                                                 out, B, T);
}

// Round 7
// 233.071 us; speedup vs baseline: 1.4124x; 1.2559x over previous
//
#include <hip/hip_runtime.h>

// 2-layer LSTM (H=2, I=1) + dense sigmoid head.
// 4 lanes per chain (sub = layer*2 + comp), DPP quad_perm exchange.
// HYBRID step: gates via exp2 (as r4), but cell update kept homogeneous
//   c' = S/P,  S = A0*A2*c + A1*(e2-1),  P = A0*A1*A2   (no gate rcp!)
// tanh(c') evaluated homogeneously in (S,P) via exponent-bit normalization
// and depth-6 Pade; ONE rcp serves both h' and the c-carry.
// Serial trans on the h->h chain: exp2 -> rcp  (was exp2->rcp->exp2->rcp).

typedef float f2 __attribute__((ext_vector_type(2)));

__device__ __forceinline__ float fast_sigmoid(float x) {
    float e = __builtin_amdgcn_exp2f(-1.4426950408889634f * x);
    return __builtin_amdgcn_rcpf(1.0f + e);
}

template<int CTRL>
__device__ __forceinline__ float dpp_f(float v) {
    return __int_as_float(__builtin_amdgcn_update_dpp(
        0, __float_as_int(v), CTRL, 0xF, 0xF, true));
}
// 0xB1 = [1,0,3,2] partner comp, same layer
// 0x44 = [0,1,0,1] lanes 2,3 <- lanes 0,1 (h0 own-order)
// 0x11 = [1,0,1,0] lanes 2,3 <- lanes 1,0 (h0 cross-order)

__global__ __launch_bounds__(256, 1)
void lstm2_hyb_kernel(const float* __restrict__ x,
                      const float* __restrict__ Wih0, const float* __restrict__ Whh0,
                      const float* __restrict__ bih0, const float* __restrict__ bhh0,
                      const float* __restrict__ Wih1, const float* __restrict__ Whh1,
                      const float* __restrict__ bih1, const float* __restrict__ bhh1,
                      const float* __restrict__ Wd,   const float* __restrict__ bd,
                      float* __restrict__ out, int B, int T)
{
    const int tid   = blockIdx.x * 256 + threadIdx.x;
    const int chain = tid >> 2;
    if (chain >= B) return;
    const int  sub   = tid & 3;        // 0:L0c0 1:L0c1 2:L1c0 3:L1c1
    const int  comp  = sub & 1;
    const bool is_l1 = (sub & 2) != 0;

    const float K1 = 1.4426950408889634f;
    const float K2 = 2.8853900817779268f;   // 2*log2(e)

    // Gate g: 0=i,1=f,2=u,3=o; weight row j=2g+comp.
    // Prescale: i,f,o by -K1 (e=exp2(-K1 g) -> sigma=1/(1+e));
    //           u by +K2  (e2=exp2(K2 g)   -> tanh=(e2-1)/(1+e2)).
    float wa[4], wb[4], who[4], whp[4], bsv[4];
#pragma unroll
    for (int g = 0; g < 4; ++g) {
        const int j = 2 * g + comp;
        const float s = (g == 2) ? K2 : -K1;
        if (!is_l1) {
            wa[g]  = s * Wih0[j];
            wb[g]  = 0.0f;
            who[g] = s * Whh0[2 * j + comp];
            whp[g] = s * Whh0[2 * j + 1 - comp];
            bsv[g] = s * (bih0[j] + bhh0[j]);
        } else {
            wa[g]  = s * Wih1[2 * j + comp];
            wb[g]  = s * Wih1[2 * j + 1 - comp];
            who[g] = s * Whh1[2 * j + comp];
            whp[g] = s * Whh1[2 * j + 1 - comp];
            bsv[g] = s * (bih1[j] + bhh1[j]);
        }
    }
    const f2 wA_lo = {wa[0], wa[1]},  wA_hi = {wa[2], wa[3]};
    const f2 wB_lo = {wb[0], wb[1]},  wB_hi = {wb[2], wb[3]};
    const f2 wO_lo = {who[0], who[1]}, wO_hi = {who[2], who[3]};
    const f2 wP_lo = {whp[0], whp[1]}, wP_hi = {whp[2], whp[3]};
    const f2 bs_lo = {bsv[0], bsv[1]}, bs_hi = {bsv[2], bsv[3]};

    float h = 0.f, c = 0.f;
    float hp = 0.f, ina = 0.f, inb = 0.f;

    auto step = [&](float xt) {
        const float a0 = is_l1 ? ina : xt;
        const f2 a02 = {a0, a0}, ib2 = {inb, inb}, h2 = {h, h}, hp2 = {hp, hp};
        // gate dots (h-dependent terms last)
        f2 gLo = __builtin_elementwise_fma(wB_lo, ib2,
                 __builtin_elementwise_fma(wA_lo, a02, bs_lo));
        gLo    = __builtin_elementwise_fma(wO_lo, h2,
                 __builtin_elementwise_fma(wP_lo, hp2, gLo));
        f2 gHi = __builtin_elementwise_fma(wB_hi, ib2,
                 __builtin_elementwise_fma(wA_hi, a02, bs_hi));
        gHi    = __builtin_elementwise_fma(wO_hi, h2,
                 __builtin_elementwise_fma(wP_hi, hp2, gHi));
        const float e0 = __builtin_amdgcn_exp2f(gLo.x);   // i
        const float e1 = __builtin_amdgcn_exp2f(gLo.y);   // f
        const float e2 = __builtin_amdgcn_exp2f(gHi.x);   // u
        const float e3 = __builtin_amdgcn_exp2f(gHi.y);   // o
        const float A0 = 1.f + e0, A1 = 1.f + e1, A2 = 1.f + e2, A3 = 1.f + e3;
        const float e2m1 = e2 - 1.f;
        // homogeneous cell: c' = S/P
        const float A0A2 = A0 * A2;
        const float S = fmaf(A0A2, c, A1 * e2m1);
        const float P = A0A2 * A1;              // in (1, ~2^40): always normal
        // normalize P = em * 2^E, em in [1,2); sc = 2^-E
        const unsigned ub = __float_as_uint(P);
        const float em = __uint_as_float((ub & 0x007FFFFFu) | 0x3F800000u);
        const float sc = __uint_as_float(0x7F000000u - (ub & 0x7F800000u));
        const float Sn = S * sc;                // c' = Sn/em
        const float lim = 4.5f * em;
        const float Sc = __builtin_amdgcn_fmed3f(Sn, -lim, lim);
        // tanh(Sc/em) = Sc*em*NUM/DEN  (depth-6 Pade, homogeneous)
        const float u  = Sc * Sc, v = em * em;
        const float v2 = v * v,   v3 = v2 * v;
        const float NUM = fmaf(fmaf(21.f, u, 1260.f * v), u, 10395.f * v2);
        const float DEN = fmaf(fmaf(fmaf(210.f, v, u), u, 4725.f * v2), u, 10395.f * v3);
        // one rcp for both h' and the c carry
        const float AD = A3 * DEN;
        const float G  = AD * em;
        const float rg = __builtin_amdgcn_rcpf(G);
        const float pre = (Sc * NUM) * v;       // Sc*NUM*em^2
        h = pre * rg;                           // sigma(o)*tanh(c') = Sc*NUM*em/AD
        c = Sn * (rg * AD);                     // Sn/em
        hp  = dpp_f<0xB1>(h);
        ina = dpp_f<0x44>(h);
        inb = dpp_f<0x11>(h);
    };

    const float4* xb = reinterpret_cast<const float4*>(x + (size_t)chain * (size_t)T);
    const int nT4 = T >> 2;

    float4 cur = xb[0];
    float4 nxt = xb[1];

    // Peeled t=0: layer1 result is bogus -> reset, re-propagate h.
    step(cur.x);
    if (is_l1) { h = 0.f; c = 0.f; }
    hp  = dpp_f<0xB1>(h);
    ina = dpp_f<0x44>(h);
    inb = dpp_f<0x11>(h);
    step(cur.y); step(cur.z); step(cur.w);

    for (int t4 = 1; t4 < nT4 - 1; ++t4) {
        cur = nxt;
        nxt = xb[t4 + 1];
        step(cur.x); step(cur.y); step(cur.z); step(cur.w);
    }
    cur = nxt;
    step(cur.x); step(cur.y); step(cur.z); step(cur.w);

    // Final skewed iteration: layer1 consumes h0(T-1).
    step(0.f);

    // Lane sub==2: h = h1_0, hp = h1_1.
    if (sub == 2) {
        out[chain] = fast_sigmoid(fmaf(Wd[1], hp, fmaf(Wd[0], h, bd[0])));
    }
}

extern "C" void kernel_launch(void* const* d_in, const int* in_sizes, int n_in,
                              void* d_out, int out_size, void* d_ws, size_t ws_size,
                              hipStream_t stream)
{
    const float* x    = (const float*)d_in[0];
    const float* Wih0 = (const float*)d_in[1];
    const float* Whh0 = (const float*)d_in[2];
    const float* bih0 = (const float*)d_in[3];
    const float* bhh0 = (const float*)d_in[4];
    const float* Wih1 = (const float*)d_in[5];
    const float* Whh1 = (const float*)d_in[6];
    const float* bih1 = (const float*)d_in[7];
    const float* bhh1 = (const float*)d_in[8];
    const float* Wd   = (const float*)d_in[9];
    const float* bd   = (const float*)d_in[10];
    float* out = (float*)d_out;

    const int B = out_size;            // 16384
    const int T = in_sizes[0] / B;     // 2048

    const int threads = B * 4;
    dim3 block(256), grid((threads + 255) / 256);
    lstm2_hyb_kernel<<<grid, block, 0, stream>>>(x, Wih0, Whh0, bih0, bhh0,
                                                 Wih1, Whh1, bih1, bhh1, Wd, bd,
                                                 out, B, T);
}